// Round 24
// baseline (361.477 us; speedup 1.0000x reference)
//
#include <hip/hip_runtime.h>
#include <stdint.h>

#define EDIM   1024
#define NHEAD  16
#define DHEAD  64
#define FFDIM  4096
#define SEQLEN 2048
#define NBATCH 2
#define MROWS  (NBATCH * SEQLEN)   // 4096
#define NT     (SEQLEN / 64)       // 32 key tiles

typedef __attribute__((ext_vector_type(8))) short bf16x8;
typedef __attribute__((ext_vector_type(4))) float f32x4;

static __device__ __forceinline__ unsigned short f2bf(float f) {
    union { float f; uint32_t u; } v; v.f = f;
    return (unsigned short)((v.u + 0x7fffu + ((v.u >> 16) & 1u)) >> 16);  // RNE
}

// async global->LDS, 16B per lane; LDS dest = wave-uniform base + lane*16
static __device__ __forceinline__ void gload16(const void* g, void* s) {
    __builtin_amdgcn_global_load_lds(
        (const __attribute__((address_space(1))) unsigned int*)g,
        (__attribute__((address_space(3))) unsigned int*)s,
        16, 0, 0);
}

// tanh-form GELU via fast exp: max |err| vs exact-erf GELU ~3e-4 (<< 0.1 tol)
static __device__ __forceinline__ float gelu_f(float x) {
    float z = 0.7978845608028654f * (x + 0.044715f * x * x * x);
    float e = __expf(-2.0f * fabsf(z));
    float th = (1.0f - e) / (1.0f + e);
    th = (z >= 0.0f) ? th : -th;
    return 0.5f * x * (1.0f + th);
}

// ---------------- cast f32 -> bf16 ----------------
__global__ void k_cast_bf16(const float* __restrict__ in, unsigned short* __restrict__ out, int n4) {
    int i = blockIdx.x * blockDim.x + threadIdx.x;
    if (i < n4) {
        float4 v = ((const float4*)in)[i];
        ushort4 o;
        o.x = f2bf(v.x); o.y = f2bf(v.y); o.z = f2bf(v.z); o.w = f2bf(v.w);
        ((ushort4*)out)[i] = o;
    }
}

// ------------- transpose + cast: in f32 [R][C] -> out bf16 [C][R] -------------
__global__ void k_transpose_cast(const float* __restrict__ in, unsigned short* __restrict__ out,
                                 int R, int C) {
    __shared__ float tile[32][33];
    int c0 = blockIdx.x * 32, r0 = blockIdx.y * 32;
    int tx = threadIdx.x, ty = threadIdx.y;  // block (32,8)
    #pragma unroll
    for (int i = 0; i < 32; i += 8)
        tile[ty + i][tx] = in[(size_t)(r0 + ty + i) * C + c0 + tx];
    __syncthreads();
    #pragma unroll
    for (int i = 0; i < 32; i += 8)
        out[(size_t)(c0 + ty + i) * R + r0 + tx] = f2bf(tile[tx][ty + i]);
}

// ------------- 4x fused 1024x1024 transpose+cast (z selects the weight) -------------
__global__ void k_transpose_cast4(const float* __restrict__ s0, const float* __restrict__ s1,
                                  const float* __restrict__ s2, const float* __restrict__ s3,
                                  unsigned short* __restrict__ d0, unsigned short* __restrict__ d1,
                                  unsigned short* __restrict__ d2, unsigned short* __restrict__ d3) {
    __shared__ float tile[32][33];
    const int z = blockIdx.z;
    const float* in = (z == 0) ? s0 : (z == 1) ? s1 : (z == 2) ? s2 : s3;
    unsigned short* out = (z == 0) ? d0 : (z == 1) ? d1 : (z == 2) ? d2 : d3;
    int c0 = blockIdx.x * 32, r0 = blockIdx.y * 32;
    int tx = threadIdx.x, ty = threadIdx.y;  // block (32,8)
    #pragma unroll
    for (int i = 0; i < 32; i += 8)
        tile[ty + i][tx] = in[(size_t)(r0 + ty + i) * EDIM + c0 + tx];
    __syncthreads();
    #pragma unroll
    for (int i = 0; i < 32; i += 8)
        out[(size_t)(c0 + ty + i) * EDIM + r0 + tx] = f2bf(tile[tx][ty + i]);
}

// ------------- per-head V transpose: V[b*S+s][h*64+d] -> Vt[(b*16+h)*64+d][s] -------------
__global__ void k_transpose_v(const unsigned short* __restrict__ V, int vstride,
                              unsigned short* __restrict__ Vt) {
    __shared__ unsigned short tile[32][33];
    const int bh = blockIdx.z, b = bh >> 4, h = bh & 15;
    const int s0 = blockIdx.x * 32, d0 = blockIdx.y * 32;
    const int tx = threadIdx.x, ty = threadIdx.y;  // block (32,8)
    #pragma unroll
    for (int i = 0; i < 32; i += 8)
        tile[ty + i][tx] = V[(size_t)(b * SEQLEN + s0 + ty + i) * vstride + h * DHEAD + d0 + tx];
    __syncthreads();
    #pragma unroll
    for (int i = 0; i < 32; i += 8)
        Vt[((size_t)(b * NHEAD + h) * DHEAD + d0 + ty + i) * SEQLEN + s0 + tx] = tile[tx][ty + i];
}

__global__ void k_concat_bias(const float* __restrict__ bq, const float* __restrict__ bk,
                              const float* __restrict__ bv, float* __restrict__ out) {
    int i = blockIdx.x * 256 + threadIdx.x;  // 0..3071
    const float* src = (i < 1024) ? bq : (i < 2048) ? bk : bv;
    out[i] = src[i & 1023];
}

// ---------- 128^2 counted-vmcnt GEMM (T3+T4, k_gemm256 pattern scaled down) ----------
// 4 waves (2x2), per-wave 64x64, 16 MFMA per kk-half group. LDS [2buf][2half][128][32]
// per operand = 64 KB total -> 2 blocks/CU (counted vmcnt + cross-block TLP).
// Same schedule/accounting as the verified 256^2 kernel: prologue 8 loads/thread,
// per group: s_waitcnt vmcnt(4) + raw s_barrier (never drain to 0), stage next
// K-step's matching half (4 gload16/thread), swizzled ds_read_b128 frags, 16 MFMA.
// EPI: 0 = bf16 + bias; 2 = f32 partial (SPLITK, bias on slice 0 only).
template <int EPI, int SPLITK>
__global__ __launch_bounds__(256, 2) void k_gemm_cv(
    const unsigned short* __restrict__ A,
    const unsigned short* __restrict__ Bt,
    const float* __restrict__ bias,
    void* __restrict__ Cout, int M, int N, int K)
{
    __shared__ __attribute__((aligned(16))) unsigned short Asm[2][2][128 * 32];  // 32 KB
    __shared__ __attribute__((aligned(16))) unsigned short Bsm[2][2][128 * 32];  // 32 KB

    const int nbx = gridDim.x;
    const int flat = blockIdx.y * nbx + blockIdx.x;
    const int cpx = (nbx * gridDim.y) >> 3;
    const int swz = (flat & 7) * cpx + (flat >> 3);
    const int bx = swz % nbx, by = swz / nbx;
    const int row0 = by * 128, col0 = bx * 128;
    const int kz = (SPLITK > 1) ? blockIdx.z : 0;
    const int Ksub = K / SPLITK;
    const int kbase0 = kz * Ksub;
    const int NTK = Ksub / 64;               // power of 2 for all our shapes

    const int t = threadIdx.x;
    const int lane = t & 63, w = t >> 6;     // 4 waves
    const int wm = w >> 1, wn = w & 1;       // 2x2 wave grid; wave owns 64x64
    const int l15 = lane & 15, l4 = lane >> 4;

    f32x4 acc[4][4];
    #pragma unroll
    for (int m = 0; m < 4; ++m)
        #pragma unroll
        for (int n = 0; n < 4; ++n) acc[m][n] = (f32x4){0.f, 0.f, 0.f, 0.f};

    // stage kk-half `h` of K-step `T` into buffer `nb`: 4 gload16/thread (2 A + 2 B)
    auto stage = [&](int nb, int h, int T) {
        const int k0 = kbase0 + T * 64 + h * 32;
        #pragma unroll
        for (int j = 0; j < 2; ++j) {
            const int sb = j * 256 + w * 64;       // wave-uniform slot base
            const int slot = sb + lane;
            const int r = slot >> 2;               // 0..127
            const int cs = (slot & 3) ^ (r & 3);   // pre-swizzled source chunk
            gload16(A + (size_t)(row0 + r) * K + k0 + cs * 8, &Asm[nb][h][sb * 8]);
        }
        #pragma unroll
        for (int j = 0; j < 2; ++j) {
            const int sb = j * 256 + w * 64;
            const int slot = sb + lane;
            const int r = slot >> 2;
            const int cs = (slot & 3) ^ (r & 3);
            gload16(Bt + (size_t)(col0 + r) * K + k0 + cs * 8, &Bsm[nb][h][sb * 8]);
        }
    };

    auto compute = [&](int buf, int h) {
        const int ch = (l4 ^ (l15 & 3)) << 3;      // swizzled read chunk offset
        bf16x8 bfr[4];
        #pragma unroll
        for (int n = 0; n < 4; ++n)
            bfr[n] = *(const bf16x8*)&Bsm[buf][h][(wn * 64 + n * 16 + l15) * 32 + ch];
        bf16x8 afr[4];
        #pragma unroll
        for (int m = 0; m < 4; ++m)
            afr[m] = *(const bf16x8*)&Asm[buf][h][(wm * 64 + m * 16 + l15) * 32 + ch];
        __builtin_amdgcn_s_setprio(1);
        #pragma unroll
        for (int m = 0; m < 4; ++m)
            #pragma unroll
            for (int n = 0; n < 4; ++n)
                acc[m][n] = __builtin_amdgcn_mfma_f32_16x16x32_bf16(afr[m], bfr[n], acc[m][n], 0, 0, 0);
        __builtin_amdgcn_s_setprio(0);
    };

    stage(0, 0, 0);
    stage(0, 1, 0);

    for (int T = 0; T < NTK; ++T) {
        const int buf = T & 1, nb = buf ^ 1;
        const int Tn = (T + 1) & (NTK - 1);    // tail wraps: wasted-but-valid loads
        asm volatile("s_waitcnt vmcnt(4)" ::: "memory");
        __builtin_amdgcn_s_barrier();
        stage(nb, 0, Tn);
        compute(buf, 0);
        asm volatile("s_waitcnt vmcnt(4)" ::: "memory");
        __builtin_amdgcn_s_barrier();
        stage(nb, 1, Tn);
        compute(buf, 1);
    }

    #pragma unroll
    for (int m = 0; m < 4; ++m) {
        const int rb = row0 + wm * 64 + m * 16 + l4 * 4;
        #pragma unroll
        for (int n = 0; n < 4; ++n) {
            const int c = col0 + wn * 64 + n * 16 + l15;
            const float bv = (SPLITK == 1 || kz == 0) ? bias[c] : 0.0f;
            #pragma unroll
            for (int i = 0; i < 4; ++i) {
                float v = acc[m][n][i] + bv;
                if (EPI == 2) {
                    float* outp = (float*)Cout + (size_t)kz * M * N;
                    outp[(size_t)(rb + i) * N + c] = v;
                } else {
                    ((unsigned short*)Cout)[(size_t)(rb + i) * N + c] = f2bf(v);
                }
            }
        }
    }
}

// ---------- 256^2 counted-vmcnt GEMM (T3+T4): FFN1 only (grid 16x16 = 256 blocks) ----------
__global__ __launch_bounds__(512, 2) void k_gemm256(
    const unsigned short* __restrict__ A,
    const unsigned short* __restrict__ Bt,
    const float* __restrict__ bias,
    unsigned short* __restrict__ C, int M, int N, int K)
{
    __shared__ __attribute__((aligned(16))) unsigned short Asm[2][2][256 * 32];  // 64 KB
    __shared__ __attribute__((aligned(16))) unsigned short Bsm[2][2][256 * 32];  // 64 KB

    const int nbx = gridDim.x;
    const int flat = blockIdx.y * nbx + blockIdx.x;
    const int cpx = (nbx * gridDim.y) >> 3;
    const int swz = (flat & 7) * cpx + (flat >> 3);
    const int bx = swz % nbx, by = swz / nbx;
    const int row0 = by * 256, col0 = bx * 256;

    const int t = threadIdx.x;
    const int lane = t & 63, w = t >> 6;     // 8 waves
    const int wm = w >> 2, wn = w & 3;       // 2 x 4 wave grid; wave owns 128 x 64
    const int l15 = lane & 15, l4 = lane >> 4;
    const int NTK = K / 64;

    f32x4 acc[8][4];
    #pragma unroll
    for (int m = 0; m < 8; ++m)
        #pragma unroll
        for (int n = 0; n < 4; ++n) acc[m][n] = (f32x4){0.f, 0.f, 0.f, 0.f};

    auto stage = [&](int nb, int h, int T) {
        const int k0 = T * 64 + h * 32;
        #pragma unroll
        for (int j = 0; j < 2; ++j) {
            const int sb = j * 512 + w * 64;
            const int slot = sb + lane;
            const int r = slot >> 2;
            const int cs = (slot & 3) ^ (r & 3);
            gload16(A + (size_t)(row0 + r) * K + k0 + cs * 8, &Asm[nb][h][sb * 8]);
        }
        #pragma unroll
        for (int j = 0; j < 2; ++j) {
            const int sb = j * 512 + w * 64;
            const int slot = sb + lane;
            const int r = slot >> 2;
            const int cs = (slot & 3) ^ (r & 3);
            gload16(Bt + (size_t)(col0 + r) * K + k0 + cs * 8, &Bsm[nb][h][sb * 8]);
        }
    };

    auto compute = [&](int buf, int h) {
        const int ch = (l4 ^ (l15 & 3)) << 3;
        bf16x8 bfr[4];
        #pragma unroll
        for (int n = 0; n < 4; ++n)
            bfr[n] = *(const bf16x8*)&Bsm[buf][h][(wn * 64 + n * 16 + l15) * 32 + ch];
        bf16x8 afr[8];
        #pragma unroll
        for (int m = 0; m < 8; ++m)
            afr[m] = *(const bf16x8*)&Asm[buf][h][(wm * 128 + m * 16 + l15) * 32 + ch];
        __builtin_amdgcn_s_setprio(1);
        #pragma unroll
        for (int m = 0; m < 8; ++m)
            #pragma unroll
            for (int n = 0; n < 4; ++n)
                acc[m][n] = __builtin_amdgcn_mfma_f32_16x16x32_bf16(afr[m], bfr[n], acc[m][n], 0, 0, 0);
        __builtin_amdgcn_s_setprio(0);
    };

    stage(0, 0, 0);
    stage(0, 1, 0);

    for (int T = 0; T < NTK; ++T) {
        const int buf = T & 1, nb = buf ^ 1;
        const int Tn = (T + 1) & (NTK - 1);
        asm volatile("s_waitcnt vmcnt(4)" ::: "memory");
        __builtin_amdgcn_s_barrier();
        stage(nb, 0, Tn);
        compute(buf, 0);
        asm volatile("s_waitcnt vmcnt(4)" ::: "memory");
        __builtin_amdgcn_s_barrier();
        stage(nb, 1, Tn);
        compute(buf, 1);
    }

    #pragma unroll
    for (int m = 0; m < 8; ++m) {
        const int rb = row0 + wm * 128 + m * 16 + l4 * 4;
        #pragma unroll
        for (int n = 0; n < 4; ++n) {
            const int c = col0 + wn * 64 + n * 16 + l15;
            const float bv = bias[c];
            #pragma unroll
            for (int i = 0; i < 4; ++i) {
                float v = gelu_f(acc[m][n][i] + bv);
                C[(size_t)(rb + i) * N + c] = f2bf(v);
            }
        }
    }
}

// ---------------- flash attention: R17 champion + defer-max (T13) ----------------
__global__ __launch_bounds__(512, 3) void k_attn(
    const unsigned short* __restrict__ QKV,  // [B*S][3E]: q at +0, k at +E
    const unsigned short* __restrict__ Vt,   // [(b*16+h)*64 + d][S]
    const float* __restrict__ pbias,         // [H][S][S]
    const float* __restrict__ mask,          // [B][S]
    unsigned short* __restrict__ Ctx)        // [B*S][E]
{
    __shared__ __attribute__((aligned(16))) unsigned short Ksm[2][64 * 64]; // [buf][key][d] 16 KB
    __shared__ __attribute__((aligned(16))) unsigned short Vsm[2][64 * 64]; // [buf][d][key] 16 KB
    __shared__ __attribute__((aligned(16))) unsigned short Psm[8][16 * 32]; // wave-private 8 KB

    const int flat = blockIdx.x;
    const int swz = (flat & 7) * 64 + (flat >> 3);
    const int h   = swz >> 5;
    const int rem = swz & 31;
    const int b   = rem & 1;
    const int qt  = rem >> 1;

    const int t = threadIdx.x;
    const int lane = t & 63, w = t >> 6;
    const int l15 = lane & 15, l4 = lane >> 4;
    const int qrow = qt * 128 + w * 16;

    const float* pbrow = pbias + ((size_t)h * SEQLEN + qrow + l4 * 4) * SEQLEN;
    const float* mrow  = mask + b * SEQLEN;

    bf16x8 qf0, qf1;
    {
        const unsigned short* qp = QKV + (size_t)(b * SEQLEN + qrow + l15) * (3 * EDIM) + h * DHEAD + l4 * 8;
        bf16x8 r0 = *(const bf16x8*)qp;
        bf16x8 r1 = *(const bf16x8*)(qp + 32);
        #pragma unroll
        for (int e = 0; e < 8; ++e) {
            union { uint32_t u; float f; } c0, c1;
            c0.u = (uint32_t)(unsigned short)r0[e] << 16;
            c1.u = (uint32_t)(unsigned short)r1[e] << 16;
            r0[e] = (short)f2bf(c0.f * 0.125f);
            r1[e] = (short)f2bf(c1.f * 0.125f);
        }
        qf0 = r0; qf1 = r1;
    }

    f32x4 oacc[4];
    #pragma unroll
    for (int nd = 0; nd < 4; ++nd) oacc[nd] = (f32x4){0.f, 0.f, 0.f, 0.f};
    float m_run[4] = {-1e30f, -1e30f, -1e30f, -1e30f};
    float l_run[4] = {0.f, 0.f, 0.f, 0.f};

    const int srow = lane >> 3;
    const int schk = lane & 7;
    const int r7 = l15 & 7;

    auto stage = [&](int buf, int kt) {
        const int kbase = kt * 64;
        #pragma unroll
        for (int j = 0; j < 2; ++j) {
            const int q  = w * 2 + j;
            const int kv = q >> 3;
            const int g  = q & 7;
            const int row = g * 8 + srow;
            const int cg  = (schk ^ (row & 7)) * 8;
            if (kv == 0)
                gload16(QKV + (size_t)(b * SEQLEN + kbase + row) * (3 * EDIM) + EDIM + h * DHEAD + cg,
                        &Ksm[buf][g * 512]);
            else
                gload16(Vt + ((size_t)((b * NHEAD + h) * DHEAD) + row) * SEQLEN + kbase + cg,
                        &Vsm[buf][g * 512]);
        }
    };

    auto compute = [&](int buf, int kt) {
        const int kbase = kt * 64;
        float p[4][4];
        float tmax[4] = {-1e30f, -1e30f, -1e30f, -1e30f};
        #pragma unroll
        for (int n = 0; n < 4; ++n) {
            const int scol = kbase + n * 16 + l15;
            const float mk = mrow[scol];
            f32x4 z;
            #pragma unroll
            for (int i = 0; i < 4; ++i) z[i] = pbrow[(size_t)i * SEQLEN + scol] + mk;
            bf16x8 kb0 = *(const bf16x8*)&Ksm[buf][(n * 16 + l15) * 64 + ((l4 ^ r7) << 3)];
            bf16x8 kb1 = *(const bf16x8*)&Ksm[buf][(n * 16 + l15) * 64 + (((4 + l4) ^ r7) << 3)];
            z = __builtin_amdgcn_mfma_f32_16x16x32_bf16(qf0, kb0, z, 0, 0, 0);
            z = __builtin_amdgcn_mfma_f32_16x16x32_bf16(qf1, kb1, z, 0, 0, 0);
            #pragma unroll
            for (int i = 0; i < 4; ++i) {
                p[n][i] = z[i];
                tmax[i] = fmaxf(tmax[i], z[i]);
            }
        }
        float pmax[4];
        #pragma unroll
        for (int i = 0; i < 4; ++i) pmax[i] = tmax[i];
        #pragma unroll
        for (int off = 1; off < 16; off <<= 1) {
            #pragma unroll
            for (int i = 0; i < 4; ++i) pmax[i] = fmaxf(pmax[i], __shfl_xor(pmax[i], off, 64));
        }
        int need = 0;
        #pragma unroll
        for (int i = 0; i < 4; ++i) need |= (pmax[i] > m_run[i] + 8.0f) ? 1 : 0;
        if (__any(need)) {
            #pragma unroll
            for (int i = 0; i < 4; ++i) {
                float mnew = fmaxf(m_run[i], pmax[i]);
                float alpha = __expf(m_run[i] - mnew);
                m_run[i] = mnew;
                l_run[i] *= alpha;
                #pragma unroll
                for (int nd = 0; nd < 4; ++nd) oacc[nd][i] *= alpha;
            }
        }
        #pragma unroll
        for (int i = 0; i < 4; ++i) {
            float sum = 0.f;
            #pragma unroll
            for (int n = 0; n < 4; ++n) { p[n][i] = __expf(p[n][i] - m_run[i]); sum += p[n][i]; }
            #pragma unroll
            for (int off = 1; off < 16; off <<= 1) sum += __shfl_xor(sum, off, 64);
            l_run[i] += sum;
        }
        #pragma unroll
        for (int hh = 0; hh < 2; ++hh) {
            #pragma unroll
            for (int n = 0; n < 2; ++n)
                #pragma unroll
                for (int i = 0; i < 4; ++i) {
                    const int row = l4 * 4 + i;
                    const int cl = n * 16 + l15;
                    Psm[w][row * 32 + (((cl >> 3) ^ (row & 3)) << 3) + (cl & 7)] =
                        f2bf(p[2 * hh + n][i]);
                }
            bf16x8 pa = *(const bf16x8*)&Psm[w][l15 * 32 + ((l4 ^ (l15 & 3)) << 3)];
            #pragma unroll
            for (int nd = 0; nd < 4; ++nd) {
                bf16x8 vf = *(const bf16x8*)&Vsm[buf][(nd * 16 + l15) * 64 + (((hh * 4 + l4) ^ r7) << 3)];
                oacc[nd] = __builtin_amdgcn_mfma_f32_16x16x32_bf16(pa, vf, oacc[nd], 0, 0, 0);
            }
        }
    };

    stage(0, 0);
    __syncthreads();
    int buf = 0;
    for (int kt = 0; kt < NT; ++kt) {
        stage(buf ^ 1, (kt + 1) & (NT - 1));
        compute(buf, kt);
        __syncthreads();
        buf ^= 1;
    }

    #pragma unroll
    for (int nd = 0; nd < 4; ++nd)
        #pragma unroll
        for (int i = 0; i < 4; ++i) {
            float v = oacc[nd][i] / l_run[i];
            Ctx[(size_t)(b * SEQLEN + qrow + l4 * 4 + i) * EDIM + h * DHEAD + nd * 16 + l15] = f2bf(v);
        }
}

// ---------------- LayerNorm over E=1024: out = LN(X + T + T2)*g + b ----------------
template <int WRITE_BF>
__global__ __launch_bounds__(256) void k_ln(
    const float* __restrict__ X, const float* __restrict__ T, const float* __restrict__ T2,
    const float* __restrict__ gam, const float* __restrict__ bet,
    float* __restrict__ Of, unsigned short* __restrict__ Ob)
{
    const int r = blockIdx.x;
    const int t = threadIdx.x;
    const size_t base = (size_t)r * EDIM + t * 4;
    float4 xv = *(const float4*)(X + base);
    float4 tv = *(const float4*)(T + base);
    float4 t2 = *(const float4*)(T2 + base);
    float4 s = make_float4(xv.x + tv.x + t2.x, xv.y + tv.y + t2.y,
                           xv.z + tv.z + t2.z, xv.w + tv.w + t2.w);
    float sum = s.x + s.y + s.z + s.w;
    float sq  = s.x * s.x + s.y * s.y + s.z * s.z + s.w * s.w;
    #pragma unroll
    for (int off = 1; off < 64; off <<= 1) {
        sum += __shfl_xor(sum, off, 64);
        sq  += __shfl_xor(sq,  off, 64);
    }
    __shared__ float red[8];
    const int lane = t & 63, w = t >> 6;
    if (lane == 0) { red[w] = sum; red[4 + w] = sq; }
    __syncthreads();
    sum = red[0] + red[1] + red[2] + red[3];
    sq  = red[4] + red[5] + red[6] + red[7];
    const float mu = sum * (1.0f / EDIM);
    const float var = sq * (1.0f / EDIM) - mu * mu;
    const float rs = rsqrtf(var + 1e-5f);
    float4 gv = *(const float4*)(gam + t * 4);
    float4 bv = *(const float4*)(bet + t * 4);
    float4 o = make_float4((s.x - mu) * rs * gv.x + bv.x,
                           (s.y - mu) * rs * gv.y + bv.y,
                           (s.z - mu) * rs * gv.z + bv.z,
                           (s.w - mu) * rs * gv.w + bv.w);
    *(float4*)(Of + base) = o;
    if (WRITE_BF) {
        ushort4 ob;
        ob.x = f2bf(o.x); ob.y = f2bf(o.y); ob.z = f2bf(o.z); ob.w = f2bf(o.w);
        *(ushort4*)(Ob + base) = ob;
    }
}

extern "C" void kernel_launch(void* const* d_in, const int* in_sizes, int n_in,
                              void* d_out, int out_size, void* d_ws, size_t ws_size,
                              hipStream_t stream) {
    const float* x    = (const float*)d_in[0];
    const float* mask = (const float*)d_in[1];
    const float* pb   = (const float*)d_in[2];
    const float* Wq = (const float*)d_in[3];  const float* bq = (const float*)d_in[4];
    const float* Wk = (const float*)d_in[5];  const float* bk = (const float*)d_in[6];
    const float* Wv = (const float*)d_in[7];  const float* bv = (const float*)d_in[8];
    const float* Wo = (const float*)d_in[9];  const float* bo = (const float*)d_in[10];
    const float* g1 = (const float*)d_in[11]; const float* be1 = (const float*)d_in[12];
    const float* W1 = (const float*)d_in[13]; const float* b1 = (const float*)d_in[14];
    const float* W2 = (const float*)d_in[15]; const float* b2 = (const float*)d_in[16];
    const float* g2 = (const float*)d_in[17]; const float* be2 = (const float*)d_in[18];
    float* out = (float*)d_out;

    // workspace layout (128 MB)
    char* ws = (char*)d_ws;
    const size_t MB = 1024 * 1024;
    unsigned short* qkv  = (unsigned short*)(ws + 0);        // 24 MB
    unsigned short* gbf  = (unsigned short*)(ws + 0);        // 32 MB alias (FFN mid)
    unsigned short* wqt  = (unsigned short*)(ws + 32 * MB);
    unsigned short* wkt  = (unsigned short*)(ws + 34 * MB);
    unsigned short* wvt  = (unsigned short*)(ws + 36 * MB);
    unsigned short* wot  = (unsigned short*)(ws + 38 * MB);
    unsigned short* w1t  = (unsigned short*)(ws + 40 * MB);
    unsigned short* w2t  = (unsigned short*)(ws + 48 * MB);
    float*          bcat = (float*)(ws + 56 * MB);
    unsigned short* ctxb = (unsigned short*)(ws + 56 * MB);
    unsigned short* xb   = (unsigned short*)(ws + 64 * MB);
    unsigned short* vt   = (unsigned short*)(ws + 64 * MB);
    float*          pt0  = (float*)(ws + 72 * MB);
    float*          pt1  = (float*)(ws + 88 * MB);
    float*          hf   = (float*)(ws + 104 * MB);
    unsigned short* hb   = (unsigned short*)(ws + 120 * MB);

    const dim3 b256(256);
    const dim3 tb(32, 8);

    k_cast_bf16<<<dim3(MROWS * EDIM / 4 / 256), b256, 0, stream>>>(x, xb, MROWS * EDIM / 4);
    k_transpose_cast4<<<dim3(EDIM / 32, EDIM / 32, 4), tb, 0, stream>>>(
        Wq, Wk, Wv, Wo, wqt, wkt, wvt, wot);
    k_transpose_cast<<<dim3(FFDIM / 32, EDIM / 32), tb, 0, stream>>>(W1, w1t, EDIM, FFDIM);
    k_transpose_cast<<<dim3(EDIM / 32, FFDIM / 32), tb, 0, stream>>>(W2, w2t, FFDIM, EDIM);
    k_concat_bias<<<dim3(12), b256, 0, stream>>>(bq, bk, bv, bcat);

    // fused QKV: [4096][3072], counted-vmcnt 128^2 (grid 24x32 = 768 blocks, 2/CU)
    k_gemm_cv<0, 1><<<dim3(3 * EDIM / 128, MROWS / 128), b256, 0, stream>>>(
        xb, wqt, bcat, qkv, MROWS, 3 * EDIM, EDIM);
    k_transpose_v<<<dim3(SEQLEN / 32, DHEAD / 32, NBATCH * NHEAD), tb, 0, stream>>>(
        qkv + 2 * EDIM, 3 * EDIM, vt);

    k_attn<<<dim3(512), dim3(512), 0, stream>>>(qkv, vt, pb, mask, ctxb);

    // Wo: counted-vmcnt 128^2, split-K=2, partials -> pt0/pt1, summed in LN1
    k_gemm_cv<2, 2><<<dim3(EDIM / 128, MROWS / 128, 2), b256, 0, stream>>>(
        ctxb, wot, bo, pt0, MROWS, EDIM, EDIM);
    k_ln<1><<<dim3(MROWS), b256, 0, stream>>>(x, pt0, pt1, g1, be1, hf, hb);
    // FFN1: 256^2 counted-vmcnt GEMM (grid 16x16 = 256 blocks, exactly 1/CU)
    k_gemm256<<<dim3(FFDIM / 256, MROWS / 256), dim3(512), 0, stream>>>(
        hb, w1t, b1, gbf, MROWS, FFDIM, EDIM);
    // FFN2: counted-vmcnt 128^2, split-K=2
    k_gemm_cv<2, 2><<<dim3(EDIM / 128, MROWS / 128, 2), b256, 0, stream>>>(
        gbf, w2t, b2, pt0, MROWS, EDIM, FFDIM);
    k_ln<0><<<dim3(MROWS), b256, 0, stream>>>(hf, pt0, pt1, g2, be2, out, nullptr);
    (void)in_sizes; (void)n_in; (void)out_size; (void)ws_size;
}

// Round 25
// 343.740 us; speedup vs baseline: 1.0516x; 1.0516x over previous
//
#include <hip/hip_runtime.h>
#include <stdint.h>

#define EDIM   1024
#define NHEAD  16
#define DHEAD  64
#define FFDIM  4096
#define SEQLEN 2048
#define NBATCH 2
#define MROWS  (NBATCH * SEQLEN)   // 4096
#define NT     (SEQLEN / 64)       // 32 key tiles

typedef __attribute__((ext_vector_type(8))) short bf16x8;
typedef __attribute__((ext_vector_type(4))) float f32x4;

static __device__ __forceinline__ unsigned short f2bf(float f) {
    union { float f; uint32_t u; } v; v.f = f;
    return (unsigned short)((v.u + 0x7fffu + ((v.u >> 16) & 1u)) >> 16);  // RNE
}

// async global->LDS, 16B per lane; LDS dest = wave-uniform base + lane*16
static __device__ __forceinline__ void gload16(const void* g, void* s) {
    __builtin_amdgcn_global_load_lds(
        (const __attribute__((address_space(1))) unsigned int*)g,
        (__attribute__((address_space(3))) unsigned int*)s,
        16, 0, 0);
}

// tanh-form GELU via fast exp: max |err| vs exact-erf GELU ~3e-4 (<< 0.1 tol)
static __device__ __forceinline__ float gelu_f(float x) {
    float z = 0.7978845608028654f * (x + 0.044715f * x * x * x);
    float e = __expf(-2.0f * fabsf(z));
    float th = (1.0f - e) / (1.0f + e);
    th = (z >= 0.0f) ? th : -th;
    return 0.5f * x * (1.0f + th);
}

// ---------------- cast f32 -> bf16 ----------------
__global__ void k_cast_bf16(const float* __restrict__ in, unsigned short* __restrict__ out, int n4) {
    int i = blockIdx.x * blockDim.x + threadIdx.x;
    if (i < n4) {
        float4 v = ((const float4*)in)[i];
        ushort4 o;
        o.x = f2bf(v.x); o.y = f2bf(v.y); o.z = f2bf(v.z); o.w = f2bf(v.w);
        ((ushort4*)out)[i] = o;
    }
}

// ------------- transpose + cast: in f32 [R][C] -> out bf16 [C][R] -------------
__global__ void k_transpose_cast(const float* __restrict__ in, unsigned short* __restrict__ out,
                                 int R, int C) {
    __shared__ float tile[32][33];
    int c0 = blockIdx.x * 32, r0 = blockIdx.y * 32;
    int tx = threadIdx.x, ty = threadIdx.y;  // block (32,8)
    #pragma unroll
    for (int i = 0; i < 32; i += 8)
        tile[ty + i][tx] = in[(size_t)(r0 + ty + i) * C + c0 + tx];
    __syncthreads();
    #pragma unroll
    for (int i = 0; i < 32; i += 8)
        out[(size_t)(c0 + ty + i) * R + r0 + tx] = f2bf(tile[tx][ty + i]);
}

// ------------- 4x fused 1024x1024 transpose+cast (z selects the weight) -------------
__global__ void k_transpose_cast4(const float* __restrict__ s0, const float* __restrict__ s1,
                                  const float* __restrict__ s2, const float* __restrict__ s3,
                                  unsigned short* __restrict__ d0, unsigned short* __restrict__ d1,
                                  unsigned short* __restrict__ d2, unsigned short* __restrict__ d3) {
    __shared__ float tile[32][33];
    const int z = blockIdx.z;
    const float* in = (z == 0) ? s0 : (z == 1) ? s1 : (z == 2) ? s2 : s3;
    unsigned short* out = (z == 0) ? d0 : (z == 1) ? d1 : (z == 2) ? d2 : d3;
    int c0 = blockIdx.x * 32, r0 = blockIdx.y * 32;
    int tx = threadIdx.x, ty = threadIdx.y;  // block (32,8)
    #pragma unroll
    for (int i = 0; i < 32; i += 8)
        tile[ty + i][tx] = in[(size_t)(r0 + ty + i) * EDIM + c0 + tx];
    __syncthreads();
    #pragma unroll
    for (int i = 0; i < 32; i += 8)
        out[(size_t)(c0 + ty + i) * EDIM + r0 + tx] = f2bf(tile[tx][ty + i]);
}

// ------------- per-head V transpose: V[b*S+s][h*64+d] -> Vt[(b*16+h)*64+d][s] -------------
__global__ void k_transpose_v(const unsigned short* __restrict__ V, int vstride,
                              unsigned short* __restrict__ Vt) {
    __shared__ unsigned short tile[32][33];
    const int bh = blockIdx.z, b = bh >> 4, h = bh & 15;
    const int s0 = blockIdx.x * 32, d0 = blockIdx.y * 32;
    const int tx = threadIdx.x, ty = threadIdx.y;  // block (32,8)
    #pragma unroll
    for (int i = 0; i < 32; i += 8)
        tile[ty + i][tx] = V[(size_t)(b * SEQLEN + s0 + ty + i) * vstride + h * DHEAD + d0 + tx];
    __syncthreads();
    #pragma unroll
    for (int i = 0; i < 32; i += 8)
        Vt[((size_t)(b * NHEAD + h) * DHEAD + d0 + ty + i) * SEQLEN + s0 + tx] = tile[tx][ty + i];
}

__global__ void k_concat_bias(const float* __restrict__ bq, const float* __restrict__ bk,
                              const float* __restrict__ bv, float* __restrict__ out) {
    int i = blockIdx.x * 256 + threadIdx.x;  // 0..3071
    const float* src = (i < 1024) ? bq : (i < 2048) ? bk : bv;
    out[i] = src[i & 1023];
}

// ---------------- GEMM (m97 structure): C[M][N] = A[M][K] @ Bt[N][K]^T + bias ----------------
// XCD-aware bijective block swizzle (T1). SPLITK>1: blockIdx.z selects a K-slice and
// writes an f32 partial at Cout + z*M*N; partials summed by the downstream LayerNorm.
template <int TBM, int TBN, int EPI, int SPLITK>
__global__ __launch_bounds__(256, 3) void k_gemm(
    const unsigned short* __restrict__ A,
    const unsigned short* __restrict__ Bt,
    const float* __restrict__ bias,
    void* __restrict__ Cout, int M, int N, int K)
{
    constexpr int MR = TBM / 32, NR = TBN / 32;
    __shared__ __attribute__((aligned(16))) unsigned short Asm[TBM * 64];
    __shared__ __attribute__((aligned(16))) unsigned short Bsm[TBN * 64];

    const int nbx = gridDim.x;
    const int flat = blockIdx.y * nbx + blockIdx.x;
    const int cpx = (nbx * gridDim.y) >> 3;
    const int swz = (flat & 7) * cpx + (flat >> 3);
    const int bx = swz % nbx, by = swz / nbx;
    const int kz = (SPLITK > 1) ? blockIdx.z : 0;
    const int Ksub = K / SPLITK;

    const int row0 = by * TBM, col0 = bx * TBN;
    const int t = threadIdx.x;
    const int lane = t & 63, w = t >> 6;
    const int wm = w >> 1, wn = w & 1;          // 2x2 wave grid
    const int l15 = lane & 15, l4 = lane >> 4;
    const int sr = lane >> 3, sc = (lane & 7) * 8;   // staging lane map (8 rows x 128B)

    f32x4 acc[MR][NR];
    #pragma unroll
    for (int m = 0; m < MR; ++m)
        #pragma unroll
        for (int n = 0; n < NR; ++n) acc[m][n] = (f32x4){0.f, 0.f, 0.f, 0.f};

    for (int k0 = kz * Ksub; k0 < (kz + 1) * Ksub; k0 += 64) {
        #pragma unroll
        for (int i = 0; i < TBM / 32; ++i) {
            const int r = w * (TBM / 4) + i * 8;
            gload16(A + (size_t)(row0 + r + sr) * K + k0 + sc, &Asm[r * 64]);
        }
        #pragma unroll
        for (int i = 0; i < TBN / 32; ++i) {
            const int r = w * (TBN / 4) + i * 8;
            gload16(Bt + (size_t)(col0 + r + sr) * K + k0 + sc, &Bsm[r * 64]);
        }
        __syncthreads();
        #pragma unroll
        for (int kk = 0; kk < 64; kk += 32) {
            bf16x8 af[MR], bf[NR];
            #pragma unroll
            for (int m = 0; m < MR; ++m)
                af[m] = *(const bf16x8*)&Asm[(wm * (TBM / 2) + m * 16 + l15) * 64 + kk + l4 * 8];
            #pragma unroll
            for (int n = 0; n < NR; ++n)
                bf[n] = *(const bf16x8*)&Bsm[(wn * (TBN / 2) + n * 16 + l15) * 64 + kk + l4 * 8];
            #pragma unroll
            for (int m = 0; m < MR; ++m)
                #pragma unroll
                for (int n = 0; n < NR; ++n)
                    acc[m][n] = __builtin_amdgcn_mfma_f32_16x16x32_bf16(af[m], bf[n], acc[m][n], 0, 0, 0);
        }
        __syncthreads();
    }

    #pragma unroll
    for (int m = 0; m < MR; ++m) {
        int rb = row0 + wm * (TBM / 2) + m * 16 + l4 * 4;
        #pragma unroll
        for (int n = 0; n < NR; ++n) {
            int c = col0 + wn * (TBN / 2) + n * 16 + l15;
            float bv = (SPLITK == 1 || kz == 0) ? bias[c] : 0.0f;
            #pragma unroll
            for (int i = 0; i < 4; ++i) {
                float v = acc[m][n][i] + bv;
                if (EPI == 1) v = gelu_f(v);
                if (EPI == 2) {
                    float* outp = (float*)Cout + (size_t)kz * M * N;
                    outp[(size_t)(rb + i) * N + c] = v;
                } else {
                    ((unsigned short*)Cout)[(size_t)(rb + i) * N + c] = f2bf(v);
                }
            }
        }
    }
}

// ---------- 256^2 counted-vmcnt GEMM (T3+T4): FFN1 only (grid 16x16 = 256 blocks) ----------
// C[M][N] = gelu(A[M][K] @ Bt[N][K]^T + bias), bf16 out. 8 waves (2x4), per-wave 128x64.
// LDS [2 buf][2 kk-half][256][32] per operand = 128 KB -> 1 block/CU. Per K-step: two
// phase-groups; each: s_waitcnt vmcnt(4) + raw s_barrier (loads stay in flight across
// barriers - NEVER drained to 0), stage next K-step's matching kk-half, swizzled
// ds_read_b128 frags, setprio(1) + 32 MFMA + setprio(0). Verified R23: -5.7 us vs 2-phase.
__global__ __launch_bounds__(512, 2) void k_gemm256(
    const unsigned short* __restrict__ A,
    const unsigned short* __restrict__ Bt,
    const float* __restrict__ bias,
    unsigned short* __restrict__ C, int M, int N, int K)
{
    __shared__ __attribute__((aligned(16))) unsigned short Asm[2][2][256 * 32];  // 64 KB
    __shared__ __attribute__((aligned(16))) unsigned short Bsm[2][2][256 * 32];  // 64 KB

    const int nbx = gridDim.x;
    const int flat = blockIdx.y * nbx + blockIdx.x;
    const int cpx = (nbx * gridDim.y) >> 3;
    const int swz = (flat & 7) * cpx + (flat >> 3);
    const int bx = swz % nbx, by = swz / nbx;
    const int row0 = by * 256, col0 = bx * 256;

    const int t = threadIdx.x;
    const int lane = t & 63, w = t >> 6;     // 8 waves
    const int wm = w >> 2, wn = w & 3;       // 2 x 4 wave grid; wave owns 128 x 64
    const int l15 = lane & 15, l4 = lane >> 4;
    const int NTK = K / 64;

    f32x4 acc[8][4];
    #pragma unroll
    for (int m = 0; m < 8; ++m)
        #pragma unroll
        for (int n = 0; n < 4; ++n) acc[m][n] = (f32x4){0.f, 0.f, 0.f, 0.f};

    auto stage = [&](int nb, int h, int T) {
        const int k0 = T * 64 + h * 32;
        #pragma unroll
        for (int j = 0; j < 2; ++j) {
            const int sb = j * 512 + w * 64;       // wave-uniform slot base
            const int slot = sb + lane;
            const int r = slot >> 2;               // 0..255
            const int cs = (slot & 3) ^ (r & 3);   // pre-swizzled source chunk
            gload16(A + (size_t)(row0 + r) * K + k0 + cs * 8, &Asm[nb][h][sb * 8]);
        }
        #pragma unroll
        for (int j = 0; j < 2; ++j) {
            const int sb = j * 512 + w * 64;
            const int slot = sb + lane;
            const int r = slot >> 2;
            const int cs = (slot & 3) ^ (r & 3);
            gload16(Bt + (size_t)(col0 + r) * K + k0 + cs * 8, &Bsm[nb][h][sb * 8]);
        }
    };

    auto compute = [&](int buf, int h) {
        const int ch = (l4 ^ (l15 & 3)) << 3;      // swizzled read chunk offset
        bf16x8 bfr[4];
        #pragma unroll
        for (int n = 0; n < 4; ++n)
            bfr[n] = *(const bf16x8*)&Bsm[buf][h][(wn * 64 + n * 16 + l15) * 32 + ch];
        bf16x8 afr[8];
        #pragma unroll
        for (int m = 0; m < 8; ++m)
            afr[m] = *(const bf16x8*)&Asm[buf][h][(wm * 128 + m * 16 + l15) * 32 + ch];
        __builtin_amdgcn_s_setprio(1);
        #pragma unroll
        for (int m = 0; m < 8; ++m)
            #pragma unroll
            for (int n = 0; n < 4; ++n)
                acc[m][n] = __builtin_amdgcn_mfma_f32_16x16x32_bf16(afr[m], bfr[n], acc[m][n], 0, 0, 0);
        __builtin_amdgcn_s_setprio(0);
    };

    stage(0, 0, 0);
    stage(0, 1, 0);

    for (int T = 0; T < NTK; ++T) {
        const int buf = T & 1, nb = buf ^ 1;
        const int Tn = (T + 1) & (NTK - 1);    // tail wraps: wasted-but-valid loads
        asm volatile("s_waitcnt vmcnt(4)" ::: "memory");  // kk0(T) landed; kk1(T) in flight
        __builtin_amdgcn_s_barrier();
        stage(nb, 0, Tn);
        compute(buf, 0);
        asm volatile("s_waitcnt vmcnt(4)" ::: "memory");  // kk1(T) landed
        __builtin_amdgcn_s_barrier();
        stage(nb, 1, Tn);
        compute(buf, 1);
    }

    #pragma unroll
    for (int m = 0; m < 8; ++m) {
        const int rb = row0 + wm * 128 + m * 16 + l4 * 4;
        #pragma unroll
        for (int n = 0; n < 4; ++n) {
            const int c = col0 + wn * 64 + n * 16 + l15;
            const float bv = bias[c];
            #pragma unroll
            for (int i = 0; i < 4; ++i) {
                float v = gelu_f(acc[m][n][i] + bv);
                C[(size_t)(rb + i) * N + c] = f2bf(v);
            }
        }
    }
}

// ---------------- flash attention: R17 champion + defer-max (T13) ----------------
__global__ __launch_bounds__(512, 3) void k_attn(
    const unsigned short* __restrict__ QKV,  // [B*S][3E]: q at +0, k at +E
    const unsigned short* __restrict__ Vt,   // [(b*16+h)*64 + d][S]
    const float* __restrict__ pbias,         // [H][S][S]
    const float* __restrict__ mask,          // [B][S]
    unsigned short* __restrict__ Ctx)        // [B*S][E]
{
    __shared__ __attribute__((aligned(16))) unsigned short Ksm[2][64 * 64]; // [buf][key][d] 16 KB
    __shared__ __attribute__((aligned(16))) unsigned short Vsm[2][64 * 64]; // [buf][d][key] 16 KB
    __shared__ __attribute__((aligned(16))) unsigned short Psm[8][16 * 32]; // wave-private 8 KB

    const int flat = blockIdx.x;
    const int swz = (flat & 7) * 64 + (flat >> 3);
    const int h   = swz >> 5;
    const int rem = swz & 31;
    const int b   = rem & 1;
    const int qt  = rem >> 1;

    const int t = threadIdx.x;
    const int lane = t & 63, w = t >> 6;
    const int l15 = lane & 15, l4 = lane >> 4;
    const int qrow = qt * 128 + w * 16;

    const float* pbrow = pbias + ((size_t)h * SEQLEN + qrow + l4 * 4) * SEQLEN;
    const float* mrow  = mask + b * SEQLEN;

    bf16x8 qf0, qf1;
    {
        const unsigned short* qp = QKV + (size_t)(b * SEQLEN + qrow + l15) * (3 * EDIM) + h * DHEAD + l4 * 8;
        bf16x8 r0 = *(const bf16x8*)qp;
        bf16x8 r1 = *(const bf16x8*)(qp + 32);
        #pragma unroll
        for (int e = 0; e < 8; ++e) {
            union { uint32_t u; float f; } c0, c1;
            c0.u = (uint32_t)(unsigned short)r0[e] << 16;
            c1.u = (uint32_t)(unsigned short)r1[e] << 16;
            r0[e] = (short)f2bf(c0.f * 0.125f);
            r1[e] = (short)f2bf(c1.f * 0.125f);
        }
        qf0 = r0; qf1 = r1;
    }

    f32x4 oacc[4];
    #pragma unroll
    for (int nd = 0; nd < 4; ++nd) oacc[nd] = (f32x4){0.f, 0.f, 0.f, 0.f};
    float m_run[4] = {-1e30f, -1e30f, -1e30f, -1e30f};
    float l_run[4] = {0.f, 0.f, 0.f, 0.f};

    const int srow = lane >> 3;
    const int schk = lane & 7;
    const int r7 = l15 & 7;

    auto stage = [&](int buf, int kt) {
        const int kbase = kt * 64;
        #pragma unroll
        for (int j = 0; j < 2; ++j) {
            const int q  = w * 2 + j;
            const int kv = q >> 3;
            const int g  = q & 7;
            const int row = g * 8 + srow;
            const int cg  = (schk ^ (row & 7)) * 8;
            if (kv == 0)
                gload16(QKV + (size_t)(b * SEQLEN + kbase + row) * (3 * EDIM) + EDIM + h * DHEAD + cg,
                        &Ksm[buf][g * 512]);
            else
                gload16(Vt + ((size_t)((b * NHEAD + h) * DHEAD) + row) * SEQLEN + kbase + cg,
                        &Vsm[buf][g * 512]);
        }
    };

    auto compute = [&](int buf, int kt) {
        const int kbase = kt * 64;
        float p[4][4];
        float tmax[4] = {-1e30f, -1e30f, -1e30f, -1e30f};
        #pragma unroll
        for (int n = 0; n < 4; ++n) {
            const int scol = kbase + n * 16 + l15;
            const float mk = mrow[scol];
            f32x4 z;
            #pragma unroll
            for (int i = 0; i < 4; ++i) z[i] = pbrow[(size_t)i * SEQLEN + scol] + mk;
            bf16x8 kb0 = *(const bf16x8*)&Ksm[buf][(n * 16 + l15) * 64 + ((l4 ^ r7) << 3)];
            bf16x8 kb1 = *(const bf16x8*)&Ksm[buf][(n * 16 + l15) * 64 + (((4 + l4) ^ r7) << 3)];
            z = __builtin_amdgcn_mfma_f32_16x16x32_bf16(qf0, kb0, z, 0, 0, 0);
            z = __builtin_amdgcn_mfma_f32_16x16x32_bf16(qf1, kb1, z, 0, 0, 0);
            #pragma unroll
            for (int i = 0; i < 4; ++i) {
                p[n][i] = z[i];
                tmax[i] = fmaxf(tmax[i], z[i]);
            }
        }
        float pmax[4];
        #pragma unroll
        for (int i = 0; i < 4; ++i) pmax[i] = tmax[i];
        #pragma unroll
        for (int off = 1; off < 16; off <<= 1) {
            #pragma unroll
            for (int i = 0; i < 4; ++i) pmax[i] = fmaxf(pmax[i], __shfl_xor(pmax[i], off, 64));
        }
        int need = 0;
        #pragma unroll
        for (int i = 0; i < 4; ++i) need |= (pmax[i] > m_run[i] + 8.0f) ? 1 : 0;
        if (__any(need)) {
            #pragma unroll
            for (int i = 0; i < 4; ++i) {
                float mnew = fmaxf(m_run[i], pmax[i]);
                float alpha = __expf(m_run[i] - mnew);
                m_run[i] = mnew;
                l_run[i] *= alpha;
                #pragma unroll
                for (int nd = 0; nd < 4; ++nd) oacc[nd][i] *= alpha;
            }
        }
        #pragma unroll
        for (int i = 0; i < 4; ++i) {
            float sum = 0.f;
            #pragma unroll
            for (int n = 0; n < 4; ++n) { p[n][i] = __expf(p[n][i] - m_run[i]); sum += p[n][i]; }
            #pragma unroll
            for (int off = 1; off < 16; off <<= 1) sum += __shfl_xor(sum, off, 64);
            l_run[i] += sum;
        }
        #pragma unroll
        for (int hh = 0; hh < 2; ++hh) {
            #pragma unroll
            for (int n = 0; n < 2; ++n)
                #pragma unroll
                for (int i = 0; i < 4; ++i) {
                    const int row = l4 * 4 + i;
                    const int cl = n * 16 + l15;
                    Psm[w][row * 32 + (((cl >> 3) ^ (row & 3)) << 3) + (cl & 7)] =
                        f2bf(p[2 * hh + n][i]);
                }
            bf16x8 pa = *(const bf16x8*)&Psm[w][l15 * 32 + ((l4 ^ (l15 & 3)) << 3)];
            #pragma unroll
            for (int nd = 0; nd < 4; ++nd) {
                bf16x8 vf = *(const bf16x8*)&Vsm[buf][(nd * 16 + l15) * 64 + (((hh * 4 + l4) ^ r7) << 3)];
                oacc[nd] = __builtin_amdgcn_mfma_f32_16x16x32_bf16(pa, vf, oacc[nd], 0, 0, 0);
            }
        }
    };

    stage(0, 0);
    __syncthreads();
    int buf = 0;
    for (int kt = 0; kt < NT; ++kt) {
        stage(buf ^ 1, (kt + 1) & (NT - 1));
        compute(buf, kt);
        __syncthreads();
        buf ^= 1;
    }

    #pragma unroll
    for (int nd = 0; nd < 4; ++nd)
        #pragma unroll
        for (int i = 0; i < 4; ++i) {
            float v = oacc[nd][i] / l_run[i];
            Ctx[(size_t)(b * SEQLEN + qrow + l4 * 4 + i) * EDIM + h * DHEAD + nd * 16 + l15] = f2bf(v);
        }
}

// ---------------- LayerNorm over E=1024: out = LN(X + T + T2)*g + b ----------------
template <int WRITE_BF>
__global__ __launch_bounds__(256) void k_ln(
    const float* __restrict__ X, const float* __restrict__ T, const float* __restrict__ T2,
    const float* __restrict__ gam, const float* __restrict__ bet,
    float* __restrict__ Of, unsigned short* __restrict__ Ob)
{
    const int r = blockIdx.x;
    const int t = threadIdx.x;
    const size_t base = (size_t)r * EDIM + t * 4;
    float4 xv = *(const float4*)(X + base);
    float4 tv = *(const float4*)(T + base);
    float4 t2 = *(const float4*)(T2 + base);
    float4 s = make_float4(xv.x + tv.x + t2.x, xv.y + tv.y + t2.y,
                           xv.z + tv.z + t2.z, xv.w + tv.w + t2.w);
    float sum = s.x + s.y + s.z + s.w;
    float sq  = s.x * s.x + s.y * s.y + s.z * s.z + s.w * s.w;
    #pragma unroll
    for (int off = 1; off < 64; off <<= 1) {
        sum += __shfl_xor(sum, off, 64);
        sq  += __shfl_xor(sq,  off, 64);
    }
    __shared__ float red[8];
    const int lane = t & 63, w = t >> 6;
    if (lane == 0) { red[w] = sum; red[4 + w] = sq; }
    __syncthreads();
    sum = red[0] + red[1] + red[2] + red[3];
    sq  = red[4] + red[5] + red[6] + red[7];
    const float mu = sum * (1.0f / EDIM);
    const float var = sq * (1.0f / EDIM) - mu * mu;
    const float rs = rsqrtf(var + 1e-5f);
    float4 gv = *(const float4*)(gam + t * 4);
    float4 bv = *(const float4*)(bet + t * 4);
    float4 o = make_float4((s.x - mu) * rs * gv.x + bv.x,
                           (s.y - mu) * rs * gv.y + bv.y,
                           (s.z - mu) * rs * gv.z + bv.z,
                           (s.w - mu) * rs * gv.w + bv.w);
    *(float4*)(Of + base) = o;
    if (WRITE_BF) {
        ushort4 ob;
        ob.x = f2bf(o.x); ob.y = f2bf(o.y); ob.z = f2bf(o.z); ob.w = f2bf(o.w);
        *(ushort4*)(Ob + base) = ob;
    }
}

extern "C" void kernel_launch(void* const* d_in, const int* in_sizes, int n_in,
                              void* d_out, int out_size, void* d_ws, size_t ws_size,
                              hipStream_t stream) {
    const float* x    = (const float*)d_in[0];
    const float* mask = (const float*)d_in[1];
    const float* pb   = (const float*)d_in[2];
    const float* Wq = (const float*)d_in[3];  const float* bq = (const float*)d_in[4];
    const float* Wk = (const float*)d_in[5];  const float* bk = (const float*)d_in[6];
    const float* Wv = (const float*)d_in[7];  const float* bv = (const float*)d_in[8];
    const float* Wo = (const float*)d_in[9];  const float* bo = (const float*)d_in[10];
    const float* g1 = (const float*)d_in[11]; const float* be1 = (const float*)d_in[12];
    const float* W1 = (const float*)d_in[13]; const float* b1 = (const float*)d_in[14];
    const float* W2 = (const float*)d_in[15]; const float* b2 = (const float*)d_in[16];
    const float* g2 = (const float*)d_in[17]; const float* be2 = (const float*)d_in[18];
    float* out = (float*)d_out;

    // workspace layout (128 MB)
    char* ws = (char*)d_ws;
    const size_t MB = 1024 * 1024;
    unsigned short* qkv  = (unsigned short*)(ws + 0);        // 24 MB
    unsigned short* gbf  = (unsigned short*)(ws + 0);        // 32 MB alias (FFN mid)
    unsigned short* wqt  = (unsigned short*)(ws + 32 * MB);
    unsigned short* wkt  = (unsigned short*)(ws + 34 * MB);
    unsigned short* wvt  = (unsigned short*)(ws + 36 * MB);
    unsigned short* wot  = (unsigned short*)(ws + 38 * MB);
    unsigned short* w1t  = (unsigned short*)(ws + 40 * MB);
    unsigned short* w2t  = (unsigned short*)(ws + 48 * MB);
    float*          bcat = (float*)(ws + 56 * MB);
    unsigned short* ctxb = (unsigned short*)(ws + 56 * MB);
    unsigned short* xb   = (unsigned short*)(ws + 64 * MB);
    unsigned short* vt   = (unsigned short*)(ws + 64 * MB);
    float*          pt0  = (float*)(ws + 72 * MB);
    float*          pt1  = (float*)(ws + 88 * MB);
    float*          hf   = (float*)(ws + 104 * MB);
    unsigned short* hb   = (unsigned short*)(ws + 120 * MB);

    const dim3 b256(256);
    const dim3 tb(32, 8);

    k_cast_bf16<<<dim3(MROWS * EDIM / 4 / 256), b256, 0, stream>>>(x, xb, MROWS * EDIM / 4);
    k_transpose_cast4<<<dim3(EDIM / 32, EDIM / 32, 4), tb, 0, stream>>>(
        Wq, Wk, Wv, Wo, wqt, wkt, wvt, wot);
    k_transpose_cast<<<dim3(FFDIM / 32, EDIM / 32), tb, 0, stream>>>(W1, w1t, EDIM, FFDIM);
    k_transpose_cast<<<dim3(EDIM / 32, FFDIM / 32), tb, 0, stream>>>(W2, w2t, FFDIM, EDIM);
    k_concat_bias<<<dim3(12), b256, 0, stream>>>(bq, bk, bv, bcat);

    // fused QKV: [4096][3072], 2-phase 128^2 (best measured for this shape)
    k_gemm<128, 128, 0, 1><<<dim3(3 * EDIM / 128, MROWS / 128), b256, 0, stream>>>(
        xb, wqt, bcat, qkv, MROWS, 3 * EDIM, EDIM);
    k_transpose_v<<<dim3(SEQLEN / 32, DHEAD / 32, NBATCH * NHEAD), tb, 0, stream>>>(
        qkv + 2 * EDIM, 3 * EDIM, vt);

    k_attn<<<dim3(512), dim3(512), 0, stream>>>(qkv, vt, pb, mask, ctxb);

    // Wo: 2-phase 128^2, split-K=2, partials -> pt0/pt1, summed in LN1
    k_gemm<128, 128, 2, 2><<<dim3(EDIM / 128, MROWS / 128, 2), b256, 0, stream>>>(
        ctxb, wot, bo, pt0, MROWS, EDIM, EDIM);
    k_ln<1><<<dim3(MROWS), b256, 0, stream>>>(x, pt0, pt1, g1, be1, hf, hb);
    // FFN1: 256^2 counted-vmcnt GEMM (grid 16x16 = 256 blocks, exactly 1/CU)
    k_gemm256<<<dim3(FFDIM / 256, MROWS / 256), dim3(512), 0, stream>>>(
        hb, w1t, b1, gbf, MROWS, FFDIM, EDIM);
    // FFN2: 2-phase 128^2, split-K=2
    k_gemm<128, 128, 2, 2><<<dim3(EDIM / 128, MROWS / 128, 2), b256, 0, stream>>>(
        gbf, w2t, b2, pt0, MROWS, EDIM, FFDIM);
    k_ln<0><<<dim3(MROWS), b256, 0, stream>>>(hf, pt0, pt1, g2, be2, out, nullptr);
    (void)in_sizes; (void)n_in; (void)out_size; (void)ws_size;
}